// Round 2
// baseline (212.244 us; speedup 1.0000x reference)
//
#include <hip/hip_runtime.h>
#include <hip/hip_cooperative_groups.h>

namespace cg = cooperative_groups;

// 22-qubit QAOA state-vector sim. Register/shfl/LDS-transpose butterflies,
// fp16-packed state (computed in f32).
// R7: (1) fuse K1/K2/K3 into ONE cooperative kernel with 2 grid.sync()
// (removes 2 graph-node gaps; same 256-block grid fits all phases).
// (2) new low-bit plan for phases 1/3: element bits {0,1} live in a x4
// register index so h loads are float4 and st loads are uint4 (1KB/wave
// per instruction, was 256B dwords); bits {0,1,12,13} in registers,
// {2..7} by half2-packed shuffles, one LDS transpose whose read side puts
// LANE at bits 0..5 (both LDS sides conflict-free, identity layout, no
// swizzle needed). st memory layout stays identity -> phase 2 unchanged.
// Fallback: if cooperative launch fails, the same phases run as 3 kernels.
//   phase1: init + phase1 + layer1 bits 0-13   (hi=blockIdx slice)
//   phase2: layer1 bits 14-21 + phase2 + layer2 bits 14-21 (lo-column slice)
//   phase3: layer2 bits 0-13 + fused |c|^2*hS reduce -> one atomicAdd/block

#define NTOT    (1u << 22)
#define LO_BITS 14
#define LO      (1u << LO_BITS)   // 16384
#define HI      256u
#define GRP     64                // lo-columns per phase-2 block
#define TPB     1024
#define R       16                // complex elements per thread

typedef __fp16 h2_t __attribute__((ext_vector_type(2)));
union PkU { unsigned u; h2_t h; };

__device__ __forceinline__ unsigned pk(float x, float y) {
    PkU p; p.h = __builtin_amdgcn_cvt_pkrtz(x, y); return p.u;
}
__device__ __forceinline__ float2 unpk(unsigned v) {
    PkU p; p.u = v; return make_float2((float)p.h.x, (float)p.h.y);
}

// register butterfly on register-index bit MASK (f32)
#define REGSTAGE(MASK, CB, SB) {                                  \
    _Pragma("unroll")                                             \
    for (int r0 = 0; r0 < R; ++r0) {                              \
        if ((r0 & (MASK)) == 0) {                                 \
            const int r1 = r0 | (MASK);                           \
            float t0r = re[r0], t0i = im[r0];                     \
            float t1r = re[r1], t1i = im[r1];                     \
            re[r0] = (CB) * t0r - (SB) * t1i;                     \
            im[r0] = (CB) * t0i + (SB) * t1r;                     \
            re[r1] = (CB) * t1r - (SB) * t0i;                     \
            im[r1] = (CB) * t1i + (SB) * t0r;                     \
        } } }

// cross-lane butterfly: ONE packed-half2 shuffle per element
#define SHFLSTAGE(MASK, CB, SB) {                                 \
    _Pragma("unroll")                                             \
    for (int r = 0; r < R; ++r) {                                 \
        unsigned pv = (unsigned)__shfl_xor((int)pk(re[r], im[r]), (MASK), 64); \
        float2 p = unpk(pv);                                      \
        float tr = re[r], ti = im[r];                             \
        re[r] = (CB) * tr - (SB) * p.y;                           \
        im[r] = (CB) * ti + (SB) * p.x;                           \
    } }

// ---------------- phase 1: init + phase1 + layer-1 bits 0-13 ----------------
// initial ownership: j = rh<<12 | w<<8 | lane<<2 | rl   (r = rh*4+rl)
// post-T ownership:  j = (w>>2)<<12 | q<<8 | (w&3)<<6 | lane   (reg = q)
__device__ __forceinline__ void phase1(
    unsigned* sC, const float* __restrict__ h, const float* __restrict__ gam,
    const float* __restrict__ bet, unsigned* __restrict__ st,
    float* __restrict__ out, unsigned b)
{
    const float g1 = gam[0];
    const float cb = __cosf(bet[0]), sb = __sinf(bet[0]);
    const unsigned t = threadIdx.x, lane = t & 63u, w = t >> 6;
    const size_t base = (size_t)b * LO;
    float re[R], im[R];

    if (b == 0 && t == 0) out[0] = 0.f;   // phase-3 accumulates later

    #pragma unroll
    for (int rh = 0; rh < 4; ++rh) {
        float4 h4 = *(const float4*)(h + base +
                        (((unsigned)rh << 12) | (w << 8) | (lane << 2)));
        const float hv4[4] = {h4.x, h4.y, h4.z, h4.w};
        #pragma unroll
        for (int rl = 0; rl < 4; ++rl) {
            float s, c;
            __sincosf(g1 * hv4[rl], &s, &c);
            re[rh * 4 + rl] = c * 0x1p-11f;
            im[rh * 4 + rl] = s * 0x1p-11f;
        }
    }
    REGSTAGE(1, cb, sb)  REGSTAGE(2, cb, sb)      // j bits 0,1 (rl)
    REGSTAGE(4, cb, sb)  REGSTAGE(8, cb, sb)      // j bits 12,13 (rh)
    SHFLSTAGE(1,  cb, sb) SHFLSTAGE(2,  cb, sb)   // j bits 2,3
    SHFLSTAGE(4,  cb, sb) SHFLSTAGE(8,  cb, sb)   // j bits 4,5
    SHFLSTAGE(16, cb, sb) SHFLSTAGE(32, cb, sb)   // j bits 6,7
    // T: identity layout; writes 4x b128 contiguous, reads 16x b32 lane-major
    #pragma unroll
    for (int rh = 0; rh < 4; ++rh) {
        unsigned u4[4];
        #pragma unroll
        for (int rl = 0; rl < 4; ++rl) u4[rl] = pk(re[rh * 4 + rl], im[rh * 4 + rl]);
        *(uint4*)&sC[((unsigned)rh << 12) | (w << 8) | (lane << 2)] = *(const uint4*)u4;
    }
    __syncthreads();
    #pragma unroll
    for (int q = 0; q < R; ++q) {
        float2 v = unpk(sC[((w >> 2) << 12) | ((unsigned)q << 8) | ((w & 3u) << 6) | lane]);
        re[q] = v.x; im[q] = v.y;
    }
    REGSTAGE(1, cb, sb)  REGSTAGE(2, cb, sb)      // j bits 8,9
    REGSTAGE(4, cb, sb)  REGSTAGE(8, cb, sb)      // j bits 10,11
    #pragma unroll
    for (int q = 0; q < R; ++q)
        st[base + (((w >> 2) << 12) | ((unsigned)q << 8) | ((w & 3u) << 6) | lane)]
            = pk(re[q], im[q]);
}

// -------- phase 2: layer-1 bits 14-21 + phase2 + layer-2 bits 14-21 --------
// lane = g (lo-column -> 256B segments); wave w(4); reg r(4).
// mapping A: hi = w | r<<4 ; mapping B: hi = r | w<<4
__device__ __forceinline__ void phase2(
    unsigned* sC, const float* __restrict__ h, const float* __restrict__ gam,
    const float* __restrict__ bet, unsigned* __restrict__ st, unsigned b)
{
    const float g2  = gam[1];
    const float cb1 = __cosf(bet[0]), sb1 = __sinf(bet[0]);
    const float cb2 = __cosf(bet[1]), sb2 = __sinf(bet[1]);
    const unsigned t = threadIdx.x, g = t & 63u, w = t >> 6;  // w: 0..15
    const unsigned lo0 = b * GRP;
    float re[R], im[R], hv[R];

    // load at mapping A: 64 lanes x 4B = 256B segments
    #pragma unroll
    for (int r = 0; r < R; ++r) {
        unsigned hi = w | ((unsigned)r << 4);
        float2 v = unpk(st[(size_t)hi * LO + lo0 + g]);
        re[r] = v.x; im[r] = v.y;
    }
    // prefetch h at mapping B (needed after T1) -- hides HBM latency
    #pragma unroll
    for (int r = 0; r < R; ++r) {
        unsigned hi = (unsigned)r | (w << 4);
        hv[r] = h[(size_t)hi * LO + lo0 + g];
    }
    // layer1: hi bits 4-7 (reg @ A)
    REGSTAGE(1, cb1, sb1)  REGSTAGE(2, cb1, sb1)
    REGSTAGE(4, cb1, sb1)  REGSTAGE(8, cb1, sb1)
    // T1: A -> B
    #pragma unroll
    for (int r = 0; r < R; ++r)
        sC[g | (w << 6) | ((unsigned)r << 10)] = pk(re[r], im[r]);
    __syncthreads();
    #pragma unroll
    for (int r = 0; r < R; ++r) {
        float2 v = unpk(sC[g | ((unsigned)r << 6) | (w << 10)]);
        re[r] = v.x; im[r] = v.y;
    }
    REGSTAGE(1, cb1, sb1)  REGSTAGE(2, cb1, sb1)
    REGSTAGE(4, cb1, sb1)  REGSTAGE(8, cb1, sb1)   // hi bits 0-3; layer1 done
    // phase2 (prefetched h)
    #pragma unroll
    for (int r = 0; r < R; ++r) {
        float s, c;
        __sincosf(g2 * hv[r], &s, &c);
        float tr = re[r], ti = im[r];
        re[r] = tr * c - ti * s;
        im[r] = tr * s + ti * c;
    }
    // layer2 at B: hi bits 0-3 (reg)
    REGSTAGE(1, cb2, sb2)  REGSTAGE(2, cb2, sb2)
    REGSTAGE(4, cb2, sb2)  REGSTAGE(8, cb2, sb2)
    // T2: B -> A
    __syncthreads();
    #pragma unroll
    for (int r = 0; r < R; ++r)
        sC[g | ((unsigned)r << 6) | (w << 10)] = pk(re[r], im[r]);
    __syncthreads();
    #pragma unroll
    for (int r = 0; r < R; ++r) {
        float2 v = unpk(sC[g | (w << 6) | ((unsigned)r << 10)]);
        re[r] = v.x; im[r] = v.y;
    }
    REGSTAGE(1, cb2, sb2)  REGSTAGE(2, cb2, sb2)
    REGSTAGE(4, cb2, sb2)  REGSTAGE(8, cb2, sb2)   // hi bits 4-7; layer2 done
    // store at mapping A
    #pragma unroll
    for (int r = 0; r < R; ++r) {
        unsigned hi = w | ((unsigned)r << 4);
        st[(size_t)hi * LO + lo0 + g] = pk(re[r], im[r]);
    }
}

// -------- phase 3: layer-2 bits 0-13 + fused |c|^2 * hS -> atomicAdd --------
__device__ __forceinline__ void phase3(
    unsigned* sC, const float* __restrict__ hS, const float* __restrict__ bet,
    const unsigned* __restrict__ st, float* __restrict__ out, unsigned b)
{
    const float cb = __cosf(bet[1]), sb = __sinf(bet[1]);
    const unsigned t = threadIdx.x, lane = t & 63u, w = t >> 6;
    const size_t base = (size_t)b * LO;
    float re[R], im[R], hv[R];

    #pragma unroll
    for (int rh = 0; rh < 4; ++rh) {
        uint4 u4 = *(const uint4*)&st[base +
                        (((unsigned)rh << 12) | (w << 8) | (lane << 2))];
        const unsigned uu[4] = {u4.x, u4.y, u4.z, u4.w};
        #pragma unroll
        for (int rl = 0; rl < 4; ++rl) {
            float2 v = unpk(uu[rl]);
            re[rh * 4 + rl] = v.x; im[rh * 4 + rl] = v.y;
        }
    }
    // prefetch hS at post-T ownership (256B segments) -- hides HBM latency
    #pragma unroll
    for (int q = 0; q < R; ++q)
        hv[q] = hS[base + (((w >> 2) << 12) | ((unsigned)q << 8) | ((w & 3u) << 6) | lane)];

    REGSTAGE(1, cb, sb)  REGSTAGE(2, cb, sb)      // j bits 0,1
    REGSTAGE(4, cb, sb)  REGSTAGE(8, cb, sb)      // j bits 12,13
    SHFLSTAGE(1,  cb, sb) SHFLSTAGE(2,  cb, sb)   // j bits 2,3
    SHFLSTAGE(4,  cb, sb) SHFLSTAGE(8,  cb, sb)   // j bits 4,5
    SHFLSTAGE(16, cb, sb) SHFLSTAGE(32, cb, sb)   // j bits 6,7
    #pragma unroll
    for (int rh = 0; rh < 4; ++rh) {
        unsigned u4[4];
        #pragma unroll
        for (int rl = 0; rl < 4; ++rl) u4[rl] = pk(re[rh * 4 + rl], im[rh * 4 + rl]);
        *(uint4*)&sC[((unsigned)rh << 12) | (w << 8) | (lane << 2)] = *(const uint4*)u4;
    }
    __syncthreads();
    #pragma unroll
    for (int q = 0; q < R; ++q) {
        float2 v = unpk(sC[((w >> 2) << 12) | ((unsigned)q << 8) | ((w & 3u) << 6) | lane]);
        re[q] = v.x; im[q] = v.y;
    }
    REGSTAGE(1, cb, sb)  REGSTAGE(2, cb, sb)      // j bits 8,9
    REGSTAGE(4, cb, sb)  REGSTAGE(8, cb, sb)      // j bits 10,11
    float acc = 0.f;
    #pragma unroll
    for (int q = 0; q < R; ++q)
        acc = fmaf(re[q] * re[q] + im[q] * im[q], hv[q], acc);
    #pragma unroll
    for (int off = 32; off >= 1; off >>= 1)
        acc += __shfl_down(acc, off, 64);
    __syncthreads();                     // sC reads done; safe to reuse
    if (lane == 0) ((float*)sC)[w] = acc;
    __syncthreads();
    if (t == 0) {
        float s = 0.f;
        #pragma unroll
        for (int ww = 0; ww < (int)(TPB / 64); ++ww) s += ((float*)sC)[ww];
        unsafeAtomicAdd(out, s);   // native global_atomic_add_f32
    }
}

// ---------------- fused cooperative kernel ----------------
__global__ __launch_bounds__(TPB, 4) void k_fused(
    const float* __restrict__ h, const float* __restrict__ hS,
    const float* __restrict__ gam, const float* __restrict__ bet,
    unsigned* __restrict__ st, float* __restrict__ out)
{
    __shared__ unsigned sC[LO];   // 64 KB, reused across phases
    cg::grid_group grid = cg::this_grid();
    const unsigned b = blockIdx.x;
    phase1(sC, h, gam, bet, st, out, b);
    grid.sync();
    phase2(sC, h, gam, bet, st, b);
    grid.sync();
    phase3(sC, hS, bet, st, out, b);
}

// ---------------- fallback: three separate kernels ----------------
__global__ __launch_bounds__(TPB, 4) void k_p1(
    const float* __restrict__ h, const float* __restrict__ gam,
    const float* __restrict__ bet, unsigned* __restrict__ st,
    float* __restrict__ out)
{
    __shared__ unsigned sC[LO];
    phase1(sC, h, gam, bet, st, out, blockIdx.x);
}
__global__ __launch_bounds__(TPB, 4) void k_p2(
    const float* __restrict__ h, const float* __restrict__ gam,
    const float* __restrict__ bet, unsigned* __restrict__ st)
{
    __shared__ unsigned sC[LO];
    phase2(sC, h, gam, bet, st, blockIdx.x);
}
__global__ __launch_bounds__(TPB, 4) void k_p3(
    const float* __restrict__ hS, const float* __restrict__ bet,
    const unsigned* __restrict__ st, float* __restrict__ out)
{
    __shared__ unsigned sC[LO];
    phase3(sC, hS, bet, st, out, blockIdx.x);
}

extern "C" void kernel_launch(void* const* d_in, const int* in_sizes, int n_in,
                              void* d_out, int out_size, void* d_ws, size_t ws_size,
                              hipStream_t stream)
{
    (void)in_sizes; (void)n_in; (void)out_size; (void)ws_size;
    const float* h   = (const float*)d_in[0];
    const float* hS  = (const float*)d_in[1];
    const float* gam = (const float*)d_in[2];
    const float* bet = (const float*)d_in[3];
    unsigned* st = (unsigned*)d_ws;       // 16 MB half2 state
    float* out   = (float*)d_out;

    void* ka[] = {(void*)&h, (void*)&hS, (void*)&gam, (void*)&bet,
                  (void*)&st, (void*)&out};
    hipError_t e = hipLaunchCooperativeKernel((const void*)k_fused,
                        dim3(NTOT / LO), dim3(TPB), ka, 0, stream);
    if (e != hipSuccess) {
        // fallback: same phases as three kernels (kernel boundary = barrier)
        k_p1<<<dim3(NTOT / LO), dim3(TPB), 0, stream>>>(h, gam, bet, st, out);
        k_p2<<<dim3(LO / GRP),  dim3(TPB), 0, stream>>>(h, gam, bet, st);
        k_p3<<<dim3(NTOT / LO), dim3(TPB), 0, stream>>>(hS, bet, st, out);
    }
}

// Round 3
// 120.582 us; speedup vs baseline: 1.7602x; 1.7602x over previous
//
#include <hip/hip_runtime.h>

// 22-qubit QAOA state-vector sim. Register/shfl/LDS-transpose butterflies,
// fp16-packed state (computed in f32). Butterfly c = cb*c + i*sb*partner is
// symmetric, so each stage runs where the partner lives.
// R8: revert R7's cooperative fusion (grid.sync on 8 non-coherent XCD L2s
// cost ~95us of stalls: k_fused ran at 985 GB/s vs ~3.7 TB/s for the split
// kernels). Keep the 3-kernel structure (kernel boundary = hardware-cheap
// device barrier) and keep R7's vectorization: phase1 reads h as float4 and
// writes LDS as uint4 (1KB/wave/instr), phase3 reads st as uint4; h/hS
// prefetched at entry to hide cold-HBM latency under butterflies.
//   K1: init + phase1 + layer1 bits 0-13   (contiguous, vectorized)
//   K2: layer1 bits 14-21 + phase2 + layer2 bits 14-21 (256B strided)
//   K3: layer2 bits 0-13 + fused |c|^2*hS reduce -> one atomicAdd/block

#define NTOT    (1u << 22)
#define LO_BITS 14
#define LO      (1u << LO_BITS)   // 16384
#define HI      256u
#define GRP     64                // lo-columns per K2 block (256B segments)
#define TPB     1024
#define R       16                // complex elements per thread

typedef __fp16 h2_t __attribute__((ext_vector_type(2)));
union PkU { unsigned u; h2_t h; };

__device__ __forceinline__ unsigned pk(float x, float y) {
    PkU p; p.h = __builtin_amdgcn_cvt_pkrtz(x, y); return p.u;
}
__device__ __forceinline__ float2 unpk(unsigned v) {
    PkU p; p.u = v; return make_float2((float)p.h.x, (float)p.h.y);
}

// register butterfly on register-index bit MASK (f32)
#define REGSTAGE(MASK, CB, SB) {                                  \
    _Pragma("unroll")                                             \
    for (int r0 = 0; r0 < R; ++r0) {                              \
        if ((r0 & (MASK)) == 0) {                                 \
            const int r1 = r0 | (MASK);                           \
            float t0r = re[r0], t0i = im[r0];                     \
            float t1r = re[r1], t1i = im[r1];                     \
            re[r0] = (CB) * t0r - (SB) * t1i;                     \
            im[r0] = (CB) * t0i + (SB) * t1r;                     \
            re[r1] = (CB) * t1r - (SB) * t0i;                     \
            im[r1] = (CB) * t1i + (SB) * t0r;                     \
        } } }

// cross-lane butterfly: ONE packed-half2 shuffle per element
#define SHFLSTAGE(MASK, CB, SB) {                                 \
    _Pragma("unroll")                                             \
    for (int r = 0; r < R; ++r) {                                 \
        unsigned pv = (unsigned)__shfl_xor((int)pk(re[r], im[r]), (MASK), 64); \
        float2 p = unpk(pv);                                      \
        float tr = re[r], ti = im[r];                             \
        re[r] = (CB) * tr - (SB) * p.y;                           \
        im[r] = (CB) * ti + (SB) * p.x;                           \
    } }

// ---------------- K1: init + phase1 + layer-1 bits 0-13 ----------------
// initial ownership: j = rh<<12 | w<<8 | lane<<2 | rl   (r = rh*4+rl)
// post-T ownership:  j = (w>>2)<<12 | q<<8 | (w&3)<<6 | lane   (reg = q)
__global__ __launch_bounds__(TPB, 4) void k_p1(
    const float* __restrict__ h, const float* __restrict__ gam,
    const float* __restrict__ bet, unsigned* __restrict__ st,
    float* __restrict__ out)
{
    __shared__ unsigned sC[LO];   // 64 KB
    const float g1 = gam[0];
    const float cb = __cosf(bet[0]), sb = __sinf(bet[0]);
    const unsigned t = threadIdx.x, lane = t & 63u, w = t >> 6;
    const size_t base = (size_t)blockIdx.x * LO;
    float re[R], im[R];

    if (blockIdx.x == 0 && t == 0) out[0] = 0.f;   // K3 accumulates later

    #pragma unroll
    for (int rh = 0; rh < 4; ++rh) {
        float4 h4 = *(const float4*)(h + base +
                        (((unsigned)rh << 12) | (w << 8) | (lane << 2)));
        const float hv4[4] = {h4.x, h4.y, h4.z, h4.w};
        #pragma unroll
        for (int rl = 0; rl < 4; ++rl) {
            float s, c;
            __sincosf(g1 * hv4[rl], &s, &c);
            re[rh * 4 + rl] = c * 0x1p-11f;
            im[rh * 4 + rl] = s * 0x1p-11f;
        }
    }
    REGSTAGE(1, cb, sb)  REGSTAGE(2, cb, sb)      // j bits 0,1 (rl)
    REGSTAGE(4, cb, sb)  REGSTAGE(8, cb, sb)      // j bits 12,13 (rh)
    SHFLSTAGE(1,  cb, sb) SHFLSTAGE(2,  cb, sb)   // j bits 2,3
    SHFLSTAGE(4,  cb, sb) SHFLSTAGE(8,  cb, sb)   // j bits 4,5
    SHFLSTAGE(16, cb, sb) SHFLSTAGE(32, cb, sb)   // j bits 6,7
    // T: identity layout; writes 4x b128 contiguous, reads 16x b32 lane-major
    #pragma unroll
    for (int rh = 0; rh < 4; ++rh) {
        unsigned u4[4];
        #pragma unroll
        for (int rl = 0; rl < 4; ++rl) u4[rl] = pk(re[rh * 4 + rl], im[rh * 4 + rl]);
        *(uint4*)&sC[((unsigned)rh << 12) | (w << 8) | (lane << 2)] = *(const uint4*)u4;
    }
    __syncthreads();
    #pragma unroll
    for (int q = 0; q < R; ++q) {
        float2 v = unpk(sC[((w >> 2) << 12) | ((unsigned)q << 8) | ((w & 3u) << 6) | lane]);
        re[q] = v.x; im[q] = v.y;
    }
    REGSTAGE(1, cb, sb)  REGSTAGE(2, cb, sb)      // j bits 8,9
    REGSTAGE(4, cb, sb)  REGSTAGE(8, cb, sb)      // j bits 10,11
    #pragma unroll
    for (int q = 0; q < R; ++q)
        st[base + (((w >> 2) << 12) | ((unsigned)q << 8) | ((w & 3u) << 6) | lane)]
            = pk(re[q], im[q]);
}

// -------- K2: layer-1 bits 14-21 + phase2 + layer-2 bits 14-21 --------
// lane = g (lo-column -> 256B segments); wave w(4); reg r(4).
// mapping A: hi = w | r<<4 ; mapping B: hi = r | w<<4
__global__ __launch_bounds__(TPB, 4) void k_p2(
    const float* __restrict__ h, const float* __restrict__ gam,
    const float* __restrict__ bet, unsigned* __restrict__ st)
{
    __shared__ unsigned sC[GRP * HI];   // 16384 words, 64 KB
    const float g2  = gam[1];
    const float cb1 = __cosf(bet[0]), sb1 = __sinf(bet[0]);
    const float cb2 = __cosf(bet[1]), sb2 = __sinf(bet[1]);
    const unsigned t = threadIdx.x, g = t & 63u, w = t >> 6;  // w: 0..15
    const unsigned lo0 = blockIdx.x * GRP;
    float re[R], im[R], hv[R];

    // load at mapping A: 64 lanes x 4B = 256B segments
    #pragma unroll
    for (int r = 0; r < R; ++r) {
        unsigned hi = w | ((unsigned)r << 4);
        float2 v = unpk(st[(size_t)hi * LO + lo0 + g]);
        re[r] = v.x; im[r] = v.y;
    }
    // prefetch h at mapping B (needed after T1) -- hides HBM latency
    #pragma unroll
    for (int r = 0; r < R; ++r) {
        unsigned hi = (unsigned)r | (w << 4);
        hv[r] = h[(size_t)hi * LO + lo0 + g];
    }
    // layer1: hi bits 4-7 (reg @ A)
    REGSTAGE(1, cb1, sb1)  REGSTAGE(2, cb1, sb1)
    REGSTAGE(4, cb1, sb1)  REGSTAGE(8, cb1, sb1)
    // T1: A -> B
    #pragma unroll
    for (int r = 0; r < R; ++r)
        sC[g | (w << 6) | ((unsigned)r << 10)] = pk(re[r], im[r]);
    __syncthreads();
    #pragma unroll
    for (int r = 0; r < R; ++r) {
        float2 v = unpk(sC[g | ((unsigned)r << 6) | (w << 10)]);
        re[r] = v.x; im[r] = v.y;
    }
    REGSTAGE(1, cb1, sb1)  REGSTAGE(2, cb1, sb1)
    REGSTAGE(4, cb1, sb1)  REGSTAGE(8, cb1, sb1)   // hi bits 0-3; layer1 done
    // phase2 (prefetched h)
    #pragma unroll
    for (int r = 0; r < R; ++r) {
        float s, c;
        __sincosf(g2 * hv[r], &s, &c);
        float tr = re[r], ti = im[r];
        re[r] = tr * c - ti * s;
        im[r] = tr * s + ti * c;
    }
    // layer2 at B: hi bits 0-3 (reg)
    REGSTAGE(1, cb2, sb2)  REGSTAGE(2, cb2, sb2)
    REGSTAGE(4, cb2, sb2)  REGSTAGE(8, cb2, sb2)
    // T2: B -> A
    __syncthreads();
    #pragma unroll
    for (int r = 0; r < R; ++r)
        sC[g | ((unsigned)r << 6) | (w << 10)] = pk(re[r], im[r]);
    __syncthreads();
    #pragma unroll
    for (int r = 0; r < R; ++r) {
        float2 v = unpk(sC[g | (w << 6) | ((unsigned)r << 10)]);
        re[r] = v.x; im[r] = v.y;
    }
    REGSTAGE(1, cb2, sb2)  REGSTAGE(2, cb2, sb2)
    REGSTAGE(4, cb2, sb2)  REGSTAGE(8, cb2, sb2)   // hi bits 4-7; layer2 done
    // store at mapping A
    #pragma unroll
    for (int r = 0; r < R; ++r) {
        unsigned hi = w | ((unsigned)r << 4);
        st[(size_t)hi * LO + lo0 + g] = pk(re[r], im[r]);
    }
}

// -------- K3: layer-2 bits 0-13 + fused |c|^2 * hS -> atomicAdd --------
__global__ __launch_bounds__(TPB, 4) void k_p3(
    const float* __restrict__ hS, const float* __restrict__ bet,
    const unsigned* __restrict__ st, float* __restrict__ out)
{
    __shared__ unsigned sC[LO];   // 64 KB (reused for wave sums at the end)
    const float cb = __cosf(bet[1]), sb = __sinf(bet[1]);
    const unsigned t = threadIdx.x, lane = t & 63u, w = t >> 6;
    const size_t base = (size_t)blockIdx.x * LO;
    float re[R], im[R], hv[R];

    #pragma unroll
    for (int rh = 0; rh < 4; ++rh) {
        uint4 u4 = *(const uint4*)&st[base +
                        (((unsigned)rh << 12) | (w << 8) | (lane << 2))];
        const unsigned uu[4] = {u4.x, u4.y, u4.z, u4.w};
        #pragma unroll
        for (int rl = 0; rl < 4; ++rl) {
            float2 v = unpk(uu[rl]);
            re[rh * 4 + rl] = v.x; im[rh * 4 + rl] = v.y;
        }
    }
    // prefetch hS at post-T ownership (256B segments) -- hides HBM latency
    #pragma unroll
    for (int q = 0; q < R; ++q)
        hv[q] = hS[base + (((w >> 2) << 12) | ((unsigned)q << 8) | ((w & 3u) << 6) | lane)];

    REGSTAGE(1, cb, sb)  REGSTAGE(2, cb, sb)      // j bits 0,1
    REGSTAGE(4, cb, sb)  REGSTAGE(8, cb, sb)      // j bits 12,13
    SHFLSTAGE(1,  cb, sb) SHFLSTAGE(2,  cb, sb)   // j bits 2,3
    SHFLSTAGE(4,  cb, sb) SHFLSTAGE(8,  cb, sb)   // j bits 4,5
    SHFLSTAGE(16, cb, sb) SHFLSTAGE(32, cb, sb)   // j bits 6,7
    #pragma unroll
    for (int rh = 0; rh < 4; ++rh) {
        unsigned u4[4];
        #pragma unroll
        for (int rl = 0; rl < 4; ++rl) u4[rl] = pk(re[rh * 4 + rl], im[rh * 4 + rl]);
        *(uint4*)&sC[((unsigned)rh << 12) | (w << 8) | (lane << 2)] = *(const uint4*)u4;
    }
    __syncthreads();
    #pragma unroll
    for (int q = 0; q < R; ++q) {
        float2 v = unpk(sC[((w >> 2) << 12) | ((unsigned)q << 8) | ((w & 3u) << 6) | lane]);
        re[q] = v.x; im[q] = v.y;
    }
    REGSTAGE(1, cb, sb)  REGSTAGE(2, cb, sb)      // j bits 8,9
    REGSTAGE(4, cb, sb)  REGSTAGE(8, cb, sb)      // j bits 10,11
    float acc = 0.f;
    #pragma unroll
    for (int q = 0; q < R; ++q)
        acc = fmaf(re[q] * re[q] + im[q] * im[q], hv[q], acc);
    #pragma unroll
    for (int off = 32; off >= 1; off >>= 1)
        acc += __shfl_down(acc, off, 64);
    __syncthreads();                     // sC reads done; safe to reuse
    if (lane == 0) ((float*)sC)[w] = acc;
    __syncthreads();
    if (t == 0) {
        float s = 0.f;
        #pragma unroll
        for (int ww = 0; ww < (int)(TPB / 64); ++ww) s += ((float*)sC)[ww];
        unsafeAtomicAdd(out, s);   // native global_atomic_add_f32
    }
}

extern "C" void kernel_launch(void* const* d_in, const int* in_sizes, int n_in,
                              void* d_out, int out_size, void* d_ws, size_t ws_size,
                              hipStream_t stream)
{
    (void)in_sizes; (void)n_in; (void)out_size; (void)ws_size;
    const float* h   = (const float*)d_in[0];
    const float* hS  = (const float*)d_in[1];
    const float* gam = (const float*)d_in[2];
    const float* bet = (const float*)d_in[3];
    unsigned* st = (unsigned*)d_ws;       // 16 MB half2 state
    float* out   = (float*)d_out;

    k_p1<<<dim3(NTOT / LO), dim3(TPB), 0, stream>>>(h, gam, bet, st, out);
    k_p2<<<dim3(LO / GRP),  dim3(TPB), 0, stream>>>(h, gam, bet, st);
    k_p3<<<dim3(NTOT / LO), dim3(TPB), 0, stream>>>(hS, bet, st, out);
}